// Round 7
// baseline (841.912 us; speedup 1.0000x reference)
//
#include <hip/hip_runtime.h>

// ---------------- types ----------------
typedef float f32x4 __attribute__((ext_vector_type(4)));
typedef __bf16 bf16x8 __attribute__((ext_vector_type(8)));
typedef unsigned short u16x4 __attribute__((ext_vector_type(4)));
typedef unsigned short u16x8 __attribute__((ext_vector_type(8)));

#define HIDDEN 4096
#define NH 32
#define NKV 2
#define HD 128
#define SLEN 2048
#define BATCH 2
#define QKV_OUT 4608  // NH*HD + 2*NKV*HD
#define MROWS 4096    // BATCH*SLEN
#define ATT_SCALE 0.08838834764831845f  // 128^-0.5 (folded into Q at prep)
#define KCHUNK 1024                     // split-K chunk (16 steps of 64)

// fp32 -> bf16 (RNE) bit pattern
__device__ __forceinline__ unsigned short f2bf(float f) {
  unsigned int u = __float_as_uint(f);
  u += 0x7fffu + ((u >> 16) & 1u);
  return (unsigned short)(u >> 16);
}

__device__ __forceinline__ float bf2f(unsigned short s) {
  return __uint_as_float((unsigned int)s << 16);
}

__device__ __forceinline__ void gload16(const void* g, void* l) {
  __builtin_amdgcn_global_load_lds((const __attribute__((address_space(1))) void*)g,
                                   (__attribute__((address_space(3))) void*)l, 16, 0, 0);
}

// ---------------- fp32 -> bf16 convert ----------------
__global__ __launch_bounds__(256) void cvt_f32_bf16(const float* __restrict__ src,
                                                    unsigned short* __restrict__ dst,
                                                    int n4) {
  int stride = gridDim.x * blockDim.x;
  for (int i = blockIdx.x * blockDim.x + threadIdx.x; i < n4; i += stride) {
    float4 v = reinterpret_cast<const float4*>(src)[i];
    u16x4 o;
    o[0] = f2bf(v.x); o[1] = f2bf(v.y); o[2] = f2bf(v.z); o[3] = f2bf(v.w);
    reinterpret_cast<u16x4*>(dst)[i] = o;
  }
}

// ---------------- bf16 MFMA GEMM v2: 256x128 tile, BK=64, triple-buffered rolling ----------------
// C[M][N] = A[M][K] * B[N][K]^T (+bias). 512 threads = 8 waves (2M x 4N), per-wave 128x32.
// Stage tile kt+2 while computing kt; end-of-tile s_waitcnt vmcnt(6) (kt+1's loads had a
// full tile to land -> near-zero wait); ONE s_barrier per tile. Buffer writes target the
// buffer read two tiles ago (barrier-ordered). LDS reads bank-uniform via 3-bit XOR
// swizzle, staging pre-swizzles the global source column (rule #21).
__global__ __launch_bounds__(512, 2) void gemm_256x128(
    const unsigned short* __restrict__ A,  // bf16 bits [M][K]
    const unsigned short* __restrict__ B,  // bf16 bits [N][K]
    const float* __restrict__ bias,        // [N] or nullptr
    float* __restrict__ C,                 // fp32 [M][N]
    int M, int N, int K, int nbx) {
  __shared__ unsigned short As[3][256 * 64];  // 3 x 32KB
  __shared__ unsigned short Bs[3][128 * 64];  // 3 x 16KB  (total 144KB)

  const int tid = threadIdx.x;
  const int wave = tid >> 6, lane = tid & 63;
  const int lr = lane & 15, lg = lane >> 4;
  const int wm2 = wave >> 2, wn4 = wave & 3;

  // bijective XCD swizzle (gridDim.x % 8 == 0)
  const int qq = (int)gridDim.x >> 3;
  const int swz = ((int)blockIdx.x & 7) * qq + ((int)blockIdx.x >> 3);
  const int by = swz / nbx, bx = swz % nbx;
  const int brow = by * 256, bcol = bx * 128;

  f32x4 acc[8][2] = {};

  // staging: per wave 4 A-rows-of-8 + 2 B-rows-of-8; source col pre-swizzled
  const int lrow8 = lane >> 3;                 // row-within-8 = row&7
  const int scol = ((lane & 7) ^ lrow8) << 3;  // swizzled k col (elements)
  const unsigned short* gA[4];
  const unsigned short* gB[2];
#pragma unroll
  for (int j = 0; j < 4; ++j)
    gA[j] = A + (size_t)(brow + wave * 32 + j * 8 + lrow8) * K + scol;
#pragma unroll
  for (int j = 0; j < 2; ++j)
    gB[j] = B + (size_t)(bcol + wave * 16 + j * 8 + lrow8) * K + scol;

#define GSTAGE(buf)                                                         \
  {                                                                         \
    _Pragma("unroll") for (int j = 0; j < 4; ++j)                           \
        gload16(gA[j], &As[buf][(wave * 32 + j * 8) * 64]);                 \
    _Pragma("unroll") for (int j = 0; j < 2; ++j)                           \
        gload16(gB[j], &Bs[buf][(wave * 16 + j * 8) * 64]);                 \
    _Pragma("unroll") for (int j = 0; j < 4; ++j) gA[j] += 64;              \
    _Pragma("unroll") for (int j = 0; j < 2; ++j) gB[j] += 64;              \
  }

  const int nk = K >> 6;
  GSTAGE(0);
  GSTAGE(1);
  asm volatile("s_waitcnt vmcnt(6)" ::: "memory");  // tile 0 fully staged
  __builtin_amdgcn_s_barrier();

  int c = 0;
  for (int kt = 0; kt < nk; ++kt) {
    const int c2 = (c >= 1) ? c - 1 : c + 2;  // (c+2)%3
    if (kt + 2 < nk) GSTAGE(c2);              // rolls across the end barrier

    bf16x8 aF[8][2], bF[2][2];
#pragma unroll
    for (int kk = 0; kk < 2; ++kk) {
#pragma unroll
      for (int nf = 0; nf < 2; ++nf)
        bF[nf][kk] = *reinterpret_cast<const bf16x8*>(
            &Bs[c][(wn4 * 32 + nf * 16 + lr) * 64 + (((kk * 4 + lg) ^ (lr & 7)) << 3)]);
#pragma unroll
      for (int mf = 0; mf < 8; ++mf)
        aF[mf][kk] = *reinterpret_cast<const bf16x8*>(
            &As[c][(wm2 * 128 + mf * 16 + lr) * 64 + (((kk * 4 + lg) ^ (lr & 7)) << 3)]);
    }
#pragma unroll
    for (int kk = 0; kk < 2; ++kk)
#pragma unroll
      for (int mf = 0; mf < 8; ++mf)
#pragma unroll
        for (int nf = 0; nf < 2; ++nf)
          acc[mf][nf] = __builtin_amdgcn_mfma_f32_16x16x32_bf16(aF[mf][kk], bF[nf][kk],
                                                                acc[mf][nf], 0, 0, 0);

    // end-of-tile: guarantee kt+1 resident for next iter; keep kt+2's 6 loads in flight
    if (kt + 2 < nk) {
      asm volatile("s_waitcnt vmcnt(6)" ::: "memory");
    } else if (kt + 1 < nk) {
      asm volatile("s_waitcnt vmcnt(0)" ::: "memory");
    }
    __builtin_amdgcn_s_barrier();
    c = (c >= 2) ? 0 : c + 1;
  }
#undef GSTAGE

  // epilogue: C/D layout col=lane&15, row=(lane>>4)*4+reg
#pragma unroll
  for (int nf = 0; nf < 2; ++nf) {
    const int col = bcol + wn4 * 32 + nf * 16 + lr;
    const float bv = bias ? bias[col] : 0.0f;
#pragma unroll
    for (int mf = 0; mf < 8; ++mf) {
      const int row = brow + wm2 * 128 + mf * 16 + lg * 4;
#pragma unroll
      for (int r = 0; r < 4; ++r)
        C[(size_t)(row + r) * N + col] = acc[mf][nf][r] + bv;
    }
  }
}

// ---------------- prep: RoPE (fp32) + scale-fold + bf16 + head-major layouts ----------------
// Trig hoisted: pair-in-head index dp = tid&63 is loop-invariant -> ONE exp+sincos/thread.
__global__ __launch_bounds__(256) void prep_qkv(const float* __restrict__ mixed,
                                                const int* __restrict__ positions,
                                                unsigned short* __restrict__ Qb,
                                                unsigned short* __restrict__ Kb,
                                                unsigned short* __restrict__ Vt) {
  const int m = blockIdx.x;
  const int b = m >> 11, s = m & 2047;
  const float pos = (float)positions[m];
  const int dp = threadIdx.x & 63;  // pair index within head (d = 2*dp)
  const bool rope_lane = (dp < 32);
  float sn = 0.0f, cs = 1.0f;
  if (rope_lane) {
    const float inv = __expf(-(float)dp * 0.28782313662425572f);  // 10000^(-dp/32)
    sincosf(pos * inv, &sn, &cs);
  }
  const float2* row = reinterpret_cast<const float2*>(mixed + (size_t)m * QKV_OUT);
#pragma unroll
  for (int it = 0; it < 9; ++it) {
    const int p = it * 256 + threadIdx.x;  // pair index, 2304 total
    const int col = p * 2;
    float2 x = row[p];
    float r1 = x.x, r2 = x.y;
    const int d = col & 127;
    const bool is_v = (col >= NH * HD + NKV * HD);
    if (rope_lane && !is_v) {
      r1 = x.x * cs - x.y * sn;
      r2 = x.x * sn + x.y * cs;
    }
    if (col < NH * HD) {  // q: fold attention scale
      r1 *= ATT_SCALE;
      r2 *= ATT_SCALE;
      const int h = col >> 7;
      const unsigned int packed = (unsigned int)f2bf(r1) | ((unsigned int)f2bf(r2) << 16);
      *reinterpret_cast<unsigned int*>(
          &Qb[((size_t)(b * NH + h) * SLEN + s) * HD + d]) = packed;
    } else if (!is_v) {
      const int kv = (col - NH * HD) >> 7;
      const unsigned int packed = (unsigned int)f2bf(r1) | ((unsigned int)f2bf(r2) << 16);
      *reinterpret_cast<unsigned int*>(
          &Kb[((size_t)(b * NKV + kv) * SLEN + s) * HD + d]) = packed;
    } else {
      const int kv = (col - NH * HD - NKV * HD) >> 7;
      unsigned short* vb = Vt + ((size_t)(b * NKV + kv) * HD) * SLEN + s;
      vb[(size_t)d * SLEN] = f2bf(r1);
      vb[(size_t)(d + 1) * SLEN] = f2bf(r2);
    }
  }
}

// ---------------- bf16 MFMA flash attention v5 (r5 verbatim — known 270us) ----------------
__global__ __launch_bounds__(256) void flash_mfma(const unsigned short* __restrict__ Qb,
                                                  const unsigned short* __restrict__ Kb,
                                                  const unsigned short* __restrict__ Vt,
                                                  unsigned short* __restrict__ ctx,
                                                  unsigned short* __restrict__ Om,
                                                  float* __restrict__ Ml) {
  __shared__ unsigned short Ks[2][64 * 128];  // [key][d] swizzled, 2x16KB
  __shared__ unsigned short Vs[128 * 64];     // [d][key] swizzled, 16KB

  const int tid = threadIdx.x;
  const int wave = tid >> 6, lane = tid & 63;
  const int lr = lane & 15, lg = lane >> 4;

  // decode (qt, chunk), heavy blocks first
  const int i = blockIdx.x;
  int qt, c;
  if (i < 8) { qt = 15 - i; c = 0; }            // qt 15..8, chunk 0 (16 steps)
  else if (i < 16) { qt = 23 - i; c = 1; }      // qt 15..8, chunk 1
  else { qt = 23 - i; c = 0; }                  // qt 7..0, single chunk
  const int h = blockIdx.y, b = blockIdx.z;
  const int kv = h >> 4;  // G = 16
  const int q0 = qt * 128;
  const int s_begin = c * KCHUNK;
  const int s_end = min(KCHUNK * (c + 1), q0 + 128);
  const int nkt = (s_end - s_begin) >> 6;
  const bool single = (c == 0) && (s_end == q0 + 128);
  const int qbw = q0 + wave * 32;  // this wave's first q row

  const unsigned short* Kbase = Kb + (size_t)(b * NKV + kv) * SLEN * HD;
  const unsigned short* Vbase = Vt + (size_t)(b * NKV + kv) * HD * SLEN;

  // Q B-fragments (col = q = lr within 16-group, k = lg*8 + ks*32); pre-scaled
  bf16x8 bQ[2][4];
#pragma unroll
  for (int qg = 0; qg < 2; ++qg) {
    const unsigned short* qp =
        Qb + ((size_t)(b * NH + h) * SLEN + qbw + qg * 16 + lr) * HD;
#pragma unroll
    for (int ks = 0; ks < 4; ++ks)
      bQ[qg][ks] = *reinterpret_cast<const bf16x8*>(qp + lg * 8 + ks * 32);
  }

  f32x4 accO[2][8] = {};
  float mi[2] = {-1e30f, -1e30f}, li[2] = {0.0f, 0.0f};

  const int vrow_off = lane >> 3, vchunk = lane & 7;
#define STAGE_K(cb, t)                                                                  \
  {                                                                                     \
    const int ss = s_begin + (t) * 64;                                                  \
    _Pragma("unroll") for (int si = 0; si < 4; ++si) {                                  \
      const int krow = wave * 16 + si * 4 + lg;                                         \
      gload16(Kbase + (size_t)(ss + krow) * HD + ((lr ^ (krow & 7)) << 3),              \
              &Ks[cb][(wave * 16 + si * 4) * 128]);                                     \
    }                                                                                   \
  }
#define STAGE_V(t)                                                                      \
  {                                                                                     \
    const int ss = s_begin + (t) * 64;                                                  \
    _Pragma("unroll") for (int si = 0; si < 4; ++si) {                                  \
      const int drow = wave * 32 + si * 8 + vrow_off;                                   \
      gload16(Vbase + (size_t)drow * SLEN + ss + ((vchunk ^ (drow & 7)) << 3),          \
              &Vs[(wave * 32 + si * 8) * 64]);                                          \
    }                                                                                   \
  }

  STAGE_K(0, 0);
  __syncthreads();  // K0 ready

  for (int kt = 0; kt < nkt; ++kt) {
    const int cur = kt & 1;
    const int s0 = s_begin + kt * 64;
    STAGE_V(kt);                               // V for THIS step (ready at mid barrier)
    if (kt + 1 < nkt) STAGE_K(cur ^ 1, kt + 1);  // K prefetch for next step
    const bool part = (s0 < qbw + 32);

    f32x4 accS[2][4] = {};
    if (part) {
      // ---- S^T = K·Q^T : D[key][q], key=kb*16+lg*4+r, q=lr ----
#pragma unroll
      for (int kb = 0; kb < 4; ++kb) {
#pragma unroll
        for (int ks = 0; ks < 4; ++ks) {
          bf16x8 aK = *reinterpret_cast<const bf16x8*>(
              &Ks[cur][(kb * 16 + lr) * 128 + (((ks * 4 + lg) ^ (lr & 7)) << 3)]);
          accS[0][kb] = __builtin_amdgcn_mfma_f32_16x16x32_bf16(aK, bQ[0][ks], accS[0][kb], 0, 0, 0);
          accS[1][kb] = __builtin_amdgcn_mfma_f32_16x16x32_bf16(aK, bQ[1][ks], accS[1][kb], 0, 0, 0);
        }
      }
    }

    __syncthreads();  // mid: all QK reads of Ks[cur] done; V + next-K staged (vmcnt drain)

    if (part) {
      unsigned short* Pw = &Ks[cur][wave * 2048];  // P aliased into dead Ks[cur]

      // ---- lane-local online softmax ----
#pragma unroll
      for (int qg = 0; qg < 2; ++qg) {
        const int qrow = qbw + qg * 16 + lr;
        float v[16];
#pragma unroll
        for (int kb = 0; kb < 4; ++kb)
#pragma unroll
          for (int r = 0; r < 4; ++r) v[kb * 4 + r] = accS[qg][kb][r];
        if (s0 + 63 > qbw + qg * 16) {  // mask if last key can exceed group's FIRST row
#pragma unroll
          for (int kb = 0; kb < 4; ++kb)
#pragma unroll
            for (int r = 0; r < 4; ++r)
              if (s0 + kb * 16 + lg * 4 + r > qrow) v[kb * 4 + r] = -1e30f;
        }
        float m16 = v[0];
#pragma unroll
        for (int i2 = 1; i2 < 16; ++i2) m16 = fmaxf(m16, v[i2]);
        m16 = fmaxf(m16, __shfl_xor(m16, 16));
        m16 = fmaxf(m16, __shfl_xor(m16, 32));
        const float mnew = fmaxf(mi[qg], m16);
        const float cf = __expf(mi[qg] - mnew);
        mi[qg] = mnew;
        float rs = 0.0f;
#pragma unroll
        for (int i2 = 0; i2 < 16; ++i2) {
          const float p = __expf(v[i2] - mnew);
          v[i2] = p;
          rs += p;
        }
        rs += __shfl_xor(rs, 16);
        rs += __shfl_xor(rs, 32);
        li[qg] = li[qg] * cf + rs;
#pragma unroll
        for (int n8 = 0; n8 < 8; ++n8) accO[qg][n8] *= cf;
#pragma unroll
        for (int kb = 0; kb < 4; ++kb) {
          const int slot = (kb * 2 + (lg >> 1)) ^ (lr & 7);
          u16x4 pk;
          pk[0] = f2bf(v[kb * 4 + 0]); pk[1] = f2bf(v[kb * 4 + 1]);
          pk[2] = f2bf(v[kb * 4 + 2]); pk[3] = f2bf(v[kb * 4 + 3]);
          *reinterpret_cast<u16x4*>(
              &Pw[(qg * 16 + lr) * 64 + slot * 8 + (lg & 1) * 4]) = pk;
        }
      }

      // ---- O^T += V^T · P^T ----
      bf16x8 pa[2][2];
#pragma unroll
      for (int qg = 0; qg < 2; ++qg)
#pragma unroll
        for (int ks = 0; ks < 2; ++ks)
          pa[qg][ks] = *reinterpret_cast<const bf16x8*>(
              &Pw[(qg * 16 + lr) * 64 + (((ks * 4 + lg) ^ (lr & 7)) << 3)]);
#pragma unroll
      for (int ks = 0; ks < 2; ++ks) {
#pragma unroll
        for (int n8 = 0; n8 < 8; ++n8) {
          bf16x8 aV = *reinterpret_cast<const bf16x8*>(
              &Vs[(n8 * 16 + lr) * 64 + (((ks * 4 + lg) ^ (lr & 7)) << 3)]);
          accO[0][n8] = __builtin_amdgcn_mfma_f32_16x16x32_bf16(aV, pa[0][ks], accO[0][n8], 0, 0, 0);
          accO[1][n8] = __builtin_amdgcn_mfma_f32_16x16x32_bf16(aV, pa[1][ks], accO[1][n8], 0, 0, 0);
        }
      }
    }

    __syncthreads();  // bottom: PV readers of Vs / P-region done before reuse
  }
#undef STAGE_K
#undef STAGE_V

  if (single) {
#pragma unroll
    for (int qg = 0; qg < 2; ++qg) {
      const float inv = 1.0f / li[qg];
      unsigned short* orow =
          ctx + (size_t)(b * SLEN + qbw + qg * 16 + lr) * HIDDEN + h * HD + lg * 4;
#pragma unroll
      for (int n8 = 0; n8 < 8; ++n8) {
        u16x4 o;
#pragma unroll
        for (int r = 0; r < 4; ++r) o[r] = f2bf(accO[qg][n8][r] * inv);
        *reinterpret_cast<u16x4*>(orow + n8 * 16) = o;
      }
    }
  } else {
#pragma unroll
    for (int qg = 0; qg < 2; ++qg) {
      const int row1k = qbw + qg * 16 + lr - 1024;
      const size_t pbase = (size_t)((b * NH + h) * 2 + c) * 1024 + row1k;
      if (lg == 0) {
        Ml[pbase * 2] = mi[qg];
        Ml[pbase * 2 + 1] = li[qg];
      }
      unsigned short* prow = Om + pbase * 128 + lg * 4;
#pragma unroll
      for (int n8 = 0; n8 < 8; ++n8) {
        u16x4 o;
#pragma unroll
        for (int r = 0; r < 4; ++r) o[r] = f2bf(accO[qg][n8][r]);
        *reinterpret_cast<u16x4*>(prow + n8 * 16) = o;
      }
    }
  }
}

// ---------------- combine the two split-K partials (rows 1024..2047 per (b,h)) ----------------
__global__ __launch_bounds__(256) void combine_partials(
    const unsigned short* __restrict__ Om, const float* __restrict__ Ml,
    unsigned short* __restrict__ ctx) {
  const int g = blockIdx.x * 64 + (threadIdx.x >> 2);  // row id, 0..65535
  const int p = threadIdx.x & 3;                       // dim quarter (32 dims)
  const int row1k = g & 1023;
  const int h = (g >> 10) & 31;
  const int b = g >> 15;
  const size_t base0 = (size_t)((b * NH + h) * 2 + 0) * 1024 + row1k;
  const size_t base1 = (size_t)((b * NH + h) * 2 + 1) * 1024 + row1k;
  const float m0 = Ml[base0 * 2], l0 = Ml[base0 * 2 + 1];
  const float m1 = Ml[base1 * 2], l1 = Ml[base1 * 2 + 1];
  const float mx = fmaxf(m0, m1);
  const float w0 = __expf(m0 - mx), w1 = __expf(m1 - mx);
  const float inv = 1.0f / (w0 * l0 + w1 * l1);
  const unsigned short* n0 = Om + base0 * 128 + p * 32;
  const unsigned short* n1 = Om + base1 * 128 + p * 32;
  unsigned short* orow =
      ctx + (size_t)(b * SLEN + 1024 + row1k) * HIDDEN + h * HD + p * 32;
#pragma unroll
  for (int cch = 0; cch < 4; ++cch) {
    u16x8 a = *reinterpret_cast<const u16x8*>(n0 + cch * 8);
    u16x8 d = *reinterpret_cast<const u16x8*>(n1 + cch * 8);
    u16x8 o;
#pragma unroll
    for (int j = 0; j < 8; ++j)
      o[j] = f2bf((w0 * bf2f(a[j]) + w1 * bf2f(d[j])) * inv);
    *reinterpret_cast<u16x8*>(orow + cch * 8) = o;
  }
}

// ---------------- launch ----------------
extern "C" void kernel_launch(void* const* d_in, const int* in_sizes, int n_in,
                              void* d_out, int out_size, void* d_ws, size_t ws_size,
                              hipStream_t stream) {
  const int* positions = (const int*)d_in[0];
  const float* hidden = (const float*)d_in[1];
  const float* w_qkv = (const float*)d_in[2];
  const float* b_qkv = (const float*)d_in[3];
  const float* w_dense = (const float*)d_in[4];
  float* out = (float*)d_out;

  char* ws = (char*)d_ws;
  size_t off = 0;
  float* mixed = (float*)(ws + off);
  off += (size_t)MROWS * QKV_OUT * 4;  // 75.5 MB
  unsigned short* h_bf = (unsigned short*)(ws + off);
  off += (size_t)MROWS * HIDDEN * 2;  // 33.6 MB (reused as Qb after QKV GEMM)
  unsigned short* wq_bf = (unsigned short*)(ws + off);
  off += (size_t)QKV_OUT * HIDDEN * 2;  // 37.7 MB (reused as Om after QKV GEMM)
  unsigned short* wd_bf = (unsigned short*)(ws + off);
  off += (size_t)HIDDEN * HIDDEN * 2;  // 33.6 MB
  unsigned short* Kb = (unsigned short*)(ws + off);
  off += (size_t)BATCH * NKV * SLEN * HD * 2;  // 2 MB
  unsigned short* Vt = (unsigned short*)(ws + off);
  off += (size_t)BATCH * NKV * SLEN * HD * 2;  // 2 MB
  unsigned short* Qb = h_bf;                        // alias: h_bf dead after QKV GEMM
  unsigned short* ctx_bf = (unsigned short*)mixed;  // alias: mixed[0,33.6MB) dead after prep
  unsigned short* Om = wq_bf;                       // alias: wq_bf dead after QKV GEMM (33.6MB used)
  float* Ml = (float*)((char*)mixed + 36 * 1024 * 1024);  // alias: mixed tail, past ctx_bf

  cvt_f32_bf16<<<2048, 256, 0, stream>>>(hidden, h_bf, MROWS * HIDDEN / 4);
  cvt_f32_bf16<<<2048, 256, 0, stream>>>(w_qkv, wq_bf, QKV_OUT * HIDDEN / 4);
  cvt_f32_bf16<<<2048, 256, 0, stream>>>(w_dense, wd_bf, HIDDEN * HIDDEN / 4);

  // QKV: M=4096, N=4608 -> grid 16*36 = 576 blocks (%8==0)
  gemm_256x128<<<dim3(576), 512, 0, stream>>>(h_bf, wq_bf, b_qkv, mixed,
                                              MROWS, QKV_OUT, HIDDEN, QKV_OUT / 128);

  prep_qkv<<<MROWS, 256, 0, stream>>>(mixed, positions, Qb, Kb, Vt);

  flash_mfma<<<dim3(24, NH, BATCH), 256, 0, stream>>>(Qb, Kb, Vt, ctx_bf, Om, Ml);

  combine_partials<<<1024, 256, 0, stream>>>(Om, Ml, ctx_bf);

  // dense: M=4096, N=4096 -> grid 16*32 = 512 blocks (%8==0)
  gemm_256x128<<<dim3(512), 512, 0, stream>>>(ctx_bf, wd_bf, nullptr, out,
                                              MROWS, HIDDEN, HIDDEN, HIDDEN / 128);
}

// Round 8
// 743.524 us; speedup vs baseline: 1.1323x; 1.1323x over previous
//
#include <hip/hip_runtime.h>

// ---------------- types ----------------
typedef float f32x4 __attribute__((ext_vector_type(4)));
typedef __bf16 bf16x8 __attribute__((ext_vector_type(8)));
typedef unsigned short u16x4 __attribute__((ext_vector_type(4)));
typedef unsigned short u16x8 __attribute__((ext_vector_type(8)));

#define HIDDEN 4096
#define NH 32
#define NKV 2
#define HD 128
#define SLEN 2048
#define BATCH 2
#define QKV_OUT 4608  // NH*HD + 2*NKV*HD
#define MROWS 4096    // BATCH*SLEN
#define ATT_SCALE 0.08838834764831845f  // 128^-0.5 (folded into Q at prep)
#define KCHUNK 1024                     // split-K chunk (16 steps of 64)

// fp32 -> bf16 (RNE) bit pattern
__device__ __forceinline__ unsigned short f2bf(float f) {
  unsigned int u = __float_as_uint(f);
  u += 0x7fffu + ((u >> 16) & 1u);
  return (unsigned short)(u >> 16);
}

__device__ __forceinline__ float bf2f(unsigned short s) {
  return __uint_as_float((unsigned int)s << 16);
}

__device__ __forceinline__ void gload16(const void* g, void* l) {
  __builtin_amdgcn_global_load_lds((const __attribute__((address_space(1))) void*)g,
                                   (__attribute__((address_space(3))) void*)l, 16, 0, 0);
}

// ---------------- fp32 -> bf16 convert ----------------
__global__ __launch_bounds__(256) void cvt_f32_bf16(const float* __restrict__ src,
                                                    unsigned short* __restrict__ dst,
                                                    int n4) {
  int stride = gridDim.x * blockDim.x;
  for (int i = blockIdx.x * blockDim.x + threadIdx.x; i < n4; i += stride) {
    float4 v = reinterpret_cast<const float4*>(src)[i];
    u16x4 o;
    o[0] = f2bf(v.x); o[1] = f2bf(v.y); o[2] = f2bf(v.z); o[3] = f2bf(v.w);
    reinterpret_cast<u16x4*>(dst)[i] = o;
  }
}

// ---------------- bf16 MFMA GEMM: C[M][N] = A[M][K] * B[N][K]^T (+bias) ----------------
// m97 128x128 structure (proven ~900 TF-class). c_bf16: output dtype flag.
__global__ __launch_bounds__(256) void gemm_bf16_mfma(
    const unsigned short* __restrict__ A, const unsigned short* __restrict__ B,
    const float* __restrict__ bias, void* __restrict__ Cout, int M, int N, int K,
    int c_bf16) {
  __shared__ unsigned short as_[128 * 32];
  __shared__ unsigned short bs_[128 * 32];
  const int tid = threadIdx.x;
  const int wave = tid >> 6;
  const int lane = tid & 63;
  const int m0 = blockIdx.y * 128;
  const int n0 = blockIdx.x * 128;
  const int wm = (wave >> 1) * 64;
  const int wn = (wave & 1) * 64;

  f32x4 acc[4][4] = {};

  const int srow = wave * 32 + (lane >> 2);
  const int scol = (lane & 3) * 8;
  unsigned short* lA = as_ + wave * 1024;
  unsigned short* lB = bs_ + wave * 1024;

  const int nk = K >> 5;
  for (int kt = 0; kt < nk; ++kt) {
    const int kb = kt << 5;
    __syncthreads();
    gload16(A + (size_t)(m0 + srow) * K + kb + scol, lA);
    gload16(A + (size_t)(m0 + srow + 16) * K + kb + scol, lA + 512);
    gload16(B + (size_t)(n0 + srow) * K + kb + scol, lB);
    gload16(B + (size_t)(n0 + srow + 16) * K + kb + scol, lB + 512);
    __syncthreads();

    bf16x8 aF[4], bF[4];
#pragma unroll
    for (int m4 = 0; m4 < 4; ++m4)
      aF[m4] = *reinterpret_cast<const bf16x8*>(
          &as_[(wm + m4 * 16 + (lane & 15)) * 32 + (lane >> 4) * 8]);
#pragma unroll
    for (int n4 = 0; n4 < 4; ++n4)
      bF[n4] = *reinterpret_cast<const bf16x8*>(
          &bs_[(wn + n4 * 16 + (lane & 15)) * 32 + (lane >> 4) * 8]);
#pragma unroll
    for (int m4 = 0; m4 < 4; ++m4)
#pragma unroll
      for (int n4 = 0; n4 < 4; ++n4)
        acc[m4][n4] =
            __builtin_amdgcn_mfma_f32_16x16x32_bf16(aF[m4], bF[n4], acc[m4][n4], 0, 0, 0);
  }

#pragma unroll
  for (int m4 = 0; m4 < 4; ++m4) {
#pragma unroll
    for (int n4 = 0; n4 < 4; ++n4) {
      const int col = n0 + wn + n4 * 16 + (lane & 15);
      const float bv = bias ? bias[col] : 0.0f;
      if (c_bf16) {
        unsigned short* C = (unsigned short*)Cout;
#pragma unroll
        for (int r = 0; r < 4; ++r) {
          const int row = m0 + wm + m4 * 16 + (lane >> 4) * 4 + r;
          C[(size_t)row * N + col] = f2bf(acc[m4][n4][r] + bv);
        }
      } else {
        float* C = (float*)Cout;
#pragma unroll
        for (int r = 0; r < 4; ++r) {
          const int row = m0 + wm + m4 * 16 + (lane >> 4) * 4 + r;
          C[(size_t)row * N + col] = acc[m4][n4][r] + bv;
        }
      }
    }
  }
}

// ---------------- prep: RoPE (fp32 trig) on bf16 mixed + scale-fold + head-major ----------------
// Trig hoisted: pair-in-head index dp = tid&63 is loop-invariant -> ONE exp+sincos/thread.
__global__ __launch_bounds__(256) void prep_qkv(const unsigned short* __restrict__ mixed,
                                                const int* __restrict__ positions,
                                                unsigned short* __restrict__ Qb,
                                                unsigned short* __restrict__ Kb,
                                                unsigned short* __restrict__ Vt) {
  const int m = blockIdx.x;
  const int b = m >> 11, s = m & 2047;
  const float pos = (float)positions[m];
  const int dp = threadIdx.x & 63;  // pair index within head (d = 2*dp)
  const bool rope_lane = (dp < 32);
  float sn = 0.0f, cs = 1.0f;
  if (rope_lane) {
    const float inv = __expf(-(float)dp * 0.28782313662425572f);  // 10000^(-dp/32)
    sincosf(pos * inv, &sn, &cs);
  }
  const unsigned int* row =
      reinterpret_cast<const unsigned int*>(mixed + (size_t)m * QKV_OUT);
#pragma unroll
  for (int it = 0; it < 9; ++it) {
    const int p = it * 256 + threadIdx.x;  // pair index, 2304 total
    const int col = p * 2;
    const unsigned int pk = row[p];
    float r1 = bf2f((unsigned short)(pk & 0xffffu));
    float r2 = bf2f((unsigned short)(pk >> 16));
    const int d = col & 127;
    const bool is_v = (col >= NH * HD + NKV * HD);
    if (rope_lane && !is_v) {
      const float x1 = r1, x2 = r2;
      r1 = x1 * cs - x2 * sn;
      r2 = x1 * sn + x2 * cs;
    }
    if (col < NH * HD) {  // q: fold attention scale
      r1 *= ATT_SCALE;
      r2 *= ATT_SCALE;
      const int h = col >> 7;
      const unsigned int packed = (unsigned int)f2bf(r1) | ((unsigned int)f2bf(r2) << 16);
      *reinterpret_cast<unsigned int*>(
          &Qb[((size_t)(b * NH + h) * SLEN + s) * HD + d]) = packed;
    } else if (!is_v) {
      const int kv = (col - NH * HD) >> 7;
      const unsigned int packed = (unsigned int)f2bf(r1) | ((unsigned int)f2bf(r2) << 16);
      *reinterpret_cast<unsigned int*>(
          &Kb[((size_t)(b * NKV + kv) * SLEN + s) * HD + d]) = packed;
    } else {
      const int kv = (col - NH * HD - NKV * HD) >> 7;
      unsigned short* vb = Vt + ((size_t)(b * NKV + kv) * HD) * SLEN + s;
      vb[(size_t)d * SLEN] = f2bf(r1);
      vb[(size_t)(d + 1) * SLEN] = f2bf(r2);
    }
  }
}

// ---------------- bf16 MFMA flash attention v5 (r5 verbatim — known 270us) ----------------
__global__ __launch_bounds__(256) void flash_mfma(const unsigned short* __restrict__ Qb,
                                                  const unsigned short* __restrict__ Kb,
                                                  const unsigned short* __restrict__ Vt,
                                                  unsigned short* __restrict__ ctx,
                                                  unsigned short* __restrict__ Om,
                                                  float* __restrict__ Ml) {
  __shared__ unsigned short Ks[2][64 * 128];  // [key][d] swizzled, 2x16KB
  __shared__ unsigned short Vs[128 * 64];     // [d][key] swizzled, 16KB

  const int tid = threadIdx.x;
  const int wave = tid >> 6, lane = tid & 63;
  const int lr = lane & 15, lg = lane >> 4;

  // decode (qt, chunk), heavy blocks first
  const int i = blockIdx.x;
  int qt, c;
  if (i < 8) { qt = 15 - i; c = 0; }            // qt 15..8, chunk 0 (16 steps)
  else if (i < 16) { qt = 23 - i; c = 1; }      // qt 15..8, chunk 1
  else { qt = 23 - i; c = 0; }                  // qt 7..0, single chunk
  const int h = blockIdx.y, b = blockIdx.z;
  const int kv = h >> 4;  // G = 16
  const int q0 = qt * 128;
  const int s_begin = c * KCHUNK;
  const int s_end = min(KCHUNK * (c + 1), q0 + 128);
  const int nkt = (s_end - s_begin) >> 6;
  const bool single = (c == 0) && (s_end == q0 + 128);
  const int qbw = q0 + wave * 32;  // this wave's first q row

  const unsigned short* Kbase = Kb + (size_t)(b * NKV + kv) * SLEN * HD;
  const unsigned short* Vbase = Vt + (size_t)(b * NKV + kv) * HD * SLEN;

  // Q B-fragments (col = q = lr within 16-group, k = lg*8 + ks*32); pre-scaled
  bf16x8 bQ[2][4];
#pragma unroll
  for (int qg = 0; qg < 2; ++qg) {
    const unsigned short* qp =
        Qb + ((size_t)(b * NH + h) * SLEN + qbw + qg * 16 + lr) * HD;
#pragma unroll
    for (int ks = 0; ks < 4; ++ks)
      bQ[qg][ks] = *reinterpret_cast<const bf16x8*>(qp + lg * 8 + ks * 32);
  }

  f32x4 accO[2][8] = {};
  float mi[2] = {-1e30f, -1e30f}, li[2] = {0.0f, 0.0f};

  const int vrow_off = lane >> 3, vchunk = lane & 7;
#define STAGE_K(cb, t)                                                                  \
  {                                                                                     \
    const int ss = s_begin + (t) * 64;                                                  \
    _Pragma("unroll") for (int si = 0; si < 4; ++si) {                                  \
      const int krow = wave * 16 + si * 4 + lg;                                         \
      gload16(Kbase + (size_t)(ss + krow) * HD + ((lr ^ (krow & 7)) << 3),              \
              &Ks[cb][(wave * 16 + si * 4) * 128]);                                     \
    }                                                                                   \
  }
#define STAGE_V(t)                                                                      \
  {                                                                                     \
    const int ss = s_begin + (t) * 64;                                                  \
    _Pragma("unroll") for (int si = 0; si < 4; ++si) {                                  \
      const int drow = wave * 32 + si * 8 + vrow_off;                                   \
      gload16(Vbase + (size_t)drow * SLEN + ss + ((vchunk ^ (drow & 7)) << 3),          \
              &Vs[(wave * 32 + si * 8) * 64]);                                          \
    }                                                                                   \
  }

  STAGE_K(0, 0);
  __syncthreads();  // K0 ready

  for (int kt = 0; kt < nkt; ++kt) {
    const int cur = kt & 1;
    const int s0 = s_begin + kt * 64;
    STAGE_V(kt);                               // V for THIS step (ready at mid barrier)
    if (kt + 1 < nkt) STAGE_K(cur ^ 1, kt + 1);  // K prefetch for next step
    const bool part = (s0 < qbw + 32);

    f32x4 accS[2][4] = {};
    if (part) {
      // ---- S^T = K·Q^T : D[key][q], key=kb*16+lg*4+r, q=lr ----
#pragma unroll
      for (int kb = 0; kb < 4; ++kb) {
#pragma unroll
        for (int ks = 0; ks < 4; ++ks) {
          bf16x8 aK = *reinterpret_cast<const bf16x8*>(
              &Ks[cur][(kb * 16 + lr) * 128 + (((ks * 4 + lg) ^ (lr & 7)) << 3)]);
          accS[0][kb] = __builtin_amdgcn_mfma_f32_16x16x32_bf16(aK, bQ[0][ks], accS[0][kb], 0, 0, 0);
          accS[1][kb] = __builtin_amdgcn_mfma_f32_16x16x32_bf16(aK, bQ[1][ks], accS[1][kb], 0, 0, 0);
        }
      }
    }

    __syncthreads();  // mid: all QK reads of Ks[cur] done; V + next-K staged (vmcnt drain)

    if (part) {
      unsigned short* Pw = &Ks[cur][wave * 2048];  // P aliased into dead Ks[cur]

      // ---- lane-local online softmax ----
#pragma unroll
      for (int qg = 0; qg < 2; ++qg) {
        const int qrow = qbw + qg * 16 + lr;
        float v[16];
#pragma unroll
        for (int kb = 0; kb < 4; ++kb)
#pragma unroll
          for (int r = 0; r < 4; ++r) v[kb * 4 + r] = accS[qg][kb][r];
        if (s0 + 63 > qbw + qg * 16) {  // mask if last key can exceed group's FIRST row
#pragma unroll
          for (int kb = 0; kb < 4; ++kb)
#pragma unroll
            for (int r = 0; r < 4; ++r)
              if (s0 + kb * 16 + lg * 4 + r > qrow) v[kb * 4 + r] = -1e30f;
        }
        float m16 = v[0];
#pragma unroll
        for (int i2 = 1; i2 < 16; ++i2) m16 = fmaxf(m16, v[i2]);
        m16 = fmaxf(m16, __shfl_xor(m16, 16));
        m16 = fmaxf(m16, __shfl_xor(m16, 32));
        const float mnew = fmaxf(mi[qg], m16);
        const float cf = __expf(mi[qg] - mnew);
        mi[qg] = mnew;
        float rs = 0.0f;
#pragma unroll
        for (int i2 = 0; i2 < 16; ++i2) {
          const float p = __expf(v[i2] - mnew);
          v[i2] = p;
          rs += p;
        }
        rs += __shfl_xor(rs, 16);
        rs += __shfl_xor(rs, 32);
        li[qg] = li[qg] * cf + rs;
#pragma unroll
        for (int n8 = 0; n8 < 8; ++n8) accO[qg][n8] *= cf;
#pragma unroll
        for (int kb = 0; kb < 4; ++kb) {
          const int slot = (kb * 2 + (lg >> 1)) ^ (lr & 7);
          u16x4 pk;
          pk[0] = f2bf(v[kb * 4 + 0]); pk[1] = f2bf(v[kb * 4 + 1]);
          pk[2] = f2bf(v[kb * 4 + 2]); pk[3] = f2bf(v[kb * 4 + 3]);
          *reinterpret_cast<u16x4*>(
              &Pw[(qg * 16 + lr) * 64 + slot * 8 + (lg & 1) * 4]) = pk;
        }
      }

      // ---- O^T += V^T · P^T ----
      bf16x8 pa[2][2];
#pragma unroll
      for (int qg = 0; qg < 2; ++qg)
#pragma unroll
        for (int ks = 0; ks < 2; ++ks)
          pa[qg][ks] = *reinterpret_cast<const bf16x8*>(
              &Pw[(qg * 16 + lr) * 64 + (((ks * 4 + lg) ^ (lr & 7)) << 3)]);
#pragma unroll
      for (int ks = 0; ks < 2; ++ks) {
#pragma unroll
        for (int n8 = 0; n8 < 8; ++n8) {
          bf16x8 aV = *reinterpret_cast<const bf16x8*>(
              &Vs[(n8 * 16 + lr) * 64 + (((ks * 4 + lg) ^ (lr & 7)) << 3)]);
          accO[0][n8] = __builtin_amdgcn_mfma_f32_16x16x32_bf16(aV, pa[0][ks], accO[0][n8], 0, 0, 0);
          accO[1][n8] = __builtin_amdgcn_mfma_f32_16x16x32_bf16(aV, pa[1][ks], accO[1][n8], 0, 0, 0);
        }
      }
    }

    __syncthreads();  // bottom: PV readers of Vs / P-region done before reuse
  }
#undef STAGE_K
#undef STAGE_V

  if (single) {
#pragma unroll
    for (int qg = 0; qg < 2; ++qg) {
      const float inv = 1.0f / li[qg];
      unsigned short* orow =
          ctx + (size_t)(b * SLEN + qbw + qg * 16 + lr) * HIDDEN + h * HD + lg * 4;
#pragma unroll
      for (int n8 = 0; n8 < 8; ++n8) {
        u16x4 o;
#pragma unroll
        for (int r = 0; r < 4; ++r) o[r] = f2bf(accO[qg][n8][r] * inv);
        *reinterpret_cast<u16x4*>(orow + n8 * 16) = o;
      }
    }
  } else {
#pragma unroll
    for (int qg = 0; qg < 2; ++qg) {
      const int row1k = qbw + qg * 16 + lr - 1024;
      const size_t pbase = (size_t)((b * NH + h) * 2 + c) * 1024 + row1k;
      if (lg == 0) {
        Ml[pbase * 2] = mi[qg];
        Ml[pbase * 2 + 1] = li[qg];
      }
      unsigned short* prow = Om + pbase * 128 + lg * 4;
#pragma unroll
      for (int n8 = 0; n8 < 8; ++n8) {
        u16x4 o;
#pragma unroll
        for (int r = 0; r < 4; ++r) o[r] = f2bf(accO[qg][n8][r]);
        *reinterpret_cast<u16x4*>(prow + n8 * 16) = o;
      }
    }
  }
}

// ---------------- combine the two split-K partials (rows 1024..2047 per (b,h)) ----------------
__global__ __launch_bounds__(256) void combine_partials(
    const unsigned short* __restrict__ Om, const float* __restrict__ Ml,
    unsigned short* __restrict__ ctx) {
  const int g = blockIdx.x * 64 + (threadIdx.x >> 2);  // row id, 0..65535
  const int p = threadIdx.x & 3;                       // dim quarter (32 dims)
  const int row1k = g & 1023;
  const int h = (g >> 10) & 31;
  const int b = g >> 15;
  const size_t base0 = (size_t)((b * NH + h) * 2 + 0) * 1024 + row1k;
  const size_t base1 = (size_t)((b * NH + h) * 2 + 1) * 1024 + row1k;
  const float m0 = Ml[base0 * 2], l0 = Ml[base0 * 2 + 1];
  const float m1 = Ml[base1 * 2], l1 = Ml[base1 * 2 + 1];
  const float mx = fmaxf(m0, m1);
  const float w0 = __expf(m0 - mx), w1 = __expf(m1 - mx);
  const float inv = 1.0f / (w0 * l0 + w1 * l1);
  const unsigned short* n0 = Om + base0 * 128 + p * 32;
  const unsigned short* n1 = Om + base1 * 128 + p * 32;
  unsigned short* orow =
      ctx + (size_t)(b * SLEN + 1024 + row1k) * HIDDEN + h * HD + p * 32;
#pragma unroll
  for (int cch = 0; cch < 4; ++cch) {
    u16x8 a = *reinterpret_cast<const u16x8*>(n0 + cch * 8);
    u16x8 d = *reinterpret_cast<const u16x8*>(n1 + cch * 8);
    u16x8 o;
#pragma unroll
    for (int j = 0; j < 8; ++j)
      o[j] = f2bf((w0 * bf2f(a[j]) + w1 * bf2f(d[j])) * inv);
    *reinterpret_cast<u16x8*>(orow + cch * 8) = o;
  }
}

// ---------------- launch ----------------
extern "C" void kernel_launch(void* const* d_in, const int* in_sizes, int n_in,
                              void* d_out, int out_size, void* d_ws, size_t ws_size,
                              hipStream_t stream) {
  const int* positions = (const int*)d_in[0];
  const float* hidden = (const float*)d_in[1];
  const float* w_qkv = (const float*)d_in[2];
  const float* b_qkv = (const float*)d_in[3];
  const float* w_dense = (const float*)d_in[4];
  float* out = (float*)d_out;

  char* ws = (char*)d_ws;
  size_t off = 0;
  unsigned short* mixed = (unsigned short*)(ws + off);  // bf16 now
  off += (size_t)MROWS * QKV_OUT * 4;  // region kept 75.5 MB (bf16 uses first 37.7)
  unsigned short* h_bf = (unsigned short*)(ws + off);
  off += (size_t)MROWS * HIDDEN * 2;  // 33.6 MB (reused as Qb after QKV GEMM)
  unsigned short* wq_bf = (unsigned short*)(ws + off);
  off += (size_t)QKV_OUT * HIDDEN * 2;  // 37.7 MB (reused as Om after QKV GEMM)
  unsigned short* wd_bf = (unsigned short*)(ws + off);
  off += (size_t)HIDDEN * HIDDEN * 2;  // 33.6 MB
  unsigned short* Kb = (unsigned short*)(ws + off);
  off += (size_t)BATCH * NKV * SLEN * HD * 2;  // 2 MB
  unsigned short* Vt = (unsigned short*)(ws + off);
  off += (size_t)BATCH * NKV * SLEN * HD * 2;  // 2 MB
  unsigned short* Qb = h_bf;                        // alias: h_bf dead after QKV GEMM
  unsigned short* ctx_bf = mixed;                   // alias: mixed dead after prep (uses 33.6MB)
  unsigned short* Om = wq_bf;                       // alias: wq_bf dead after QKV GEMM
  float* Ml = (float*)((char*)mixed + 36 * 1024 * 1024);  // mixed-region tail, past ctx_bf

  cvt_f32_bf16<<<2048, 256, 0, stream>>>(hidden, h_bf, MROWS * HIDDEN / 4);
  cvt_f32_bf16<<<2048, 256, 0, stream>>>(w_qkv, wq_bf, QKV_OUT * HIDDEN / 4);
  cvt_f32_bf16<<<2048, 256, 0, stream>>>(w_dense, wd_bf, HIDDEN * HIDDEN / 4);

  gemm_bf16_mfma<<<dim3(QKV_OUT / 128, MROWS / 128), 256, 0, stream>>>(
      h_bf, wq_bf, b_qkv, mixed, MROWS, QKV_OUT, HIDDEN, 1);

  prep_qkv<<<MROWS, 256, 0, stream>>>(mixed, positions, Qb, Kb, Vt);

  flash_mfma<<<dim3(24, NH, BATCH), 256, 0, stream>>>(Qb, Kb, Vt, ctx_bf, Om, Ml);

  combine_partials<<<1024, 256, 0, stream>>>(Om, Ml, ctx_bf);

  gemm_bf16_mfma<<<dim3(HIDDEN / 128, MROWS / 128), 256, 0, stream>>>(
      ctx_bf, wd_bf, nullptr, out, MROWS, HIDDEN, HIDDEN, 0);
}